// Round 6
// baseline (3784.762 us; speedup 1.0000x reference)
//
#include <hip/hip_runtime.h>
#include <stdint.h>

// Problem constants
#define ZSIZE   8388608      // 32*256*32*32
#define NPIX    32768        // 32*32*32
#define IDX_OFF ZSIZE        // idx output offset (floats) in d_out
#define LOSS_OFF (ZSIZE + NPIX)
#define ET_OFF  1024         // Et fp32 [256][1024] scratch (for kse)
#define E1_OFF  263168       // e1s swizzled bf16 (131072 floats = 512 KB)
#define ZT_OFF  394240       // zt bf16 [32][1024][256] (4194304 floats)
#define CAP     24           // candidate slots per pixel
#define WWIN    6.0e-3f      // window >= 2*eps_bound (eps<=2.4e-3 rigorous)

using v8s = __attribute__((ext_vector_type(8))) short;   // 8 bf16 (4 VGPR)
using v4f = __attribute__((ext_vector_type(4))) float;   // MFMA acc

__device__ __forceinline__ unsigned short bf16rne(float f) {
  unsigned u = __float_as_uint(f);
  return (unsigned short)((u + 0x7FFFu + ((u >> 16) & 1u)) >> 16);
}

// ---------------------------------------------------------------------------
// ktr: transpose embedding E[1024][256] -> Et[256][1024] (feeds kse only)
// ---------------------------------------------------------------------------
__global__ __launch_bounds__(256) void ktr(const float* __restrict__ E,
                                           float* __restrict__ out) {
  __shared__ float tile[64][65];
  const int k0 = blockIdx.x * 64;
  const int c0 = blockIdx.y * 64;
  const int t = threadIdx.x;
  #pragma unroll
  for (int i = 0; i < 4; i++) {
    int f = t + 256 * i;
    int r = f >> 4, q = f & 15;
    float4 e = *(const float4*)(E + (k0 + r) * 256 + c0 + 4 * q);
    tile[r][4 * q + 0] = e.x; tile[r][4 * q + 1] = e.y;
    tile[r][4 * q + 2] = e.z; tile[r][4 * q + 3] = e.w;
  }
  __syncthreads();
  #pragma unroll
  for (int i = 0; i < 4; i++) {
    int f = t + 256 * i;
    int cr = f >> 4, kq = f & 15;
    float4 o;
    o.x = tile[4 * kq + 0][cr];
    o.y = tile[4 * kq + 1][cr];
    o.z = tile[4 * kq + 2][cr];
    o.w = tile[4 * kq + 3][cr];
    *(float4*)(out + ET_OFF + (c0 + cr) * 1024 + k0 + 4 * kq) = o;
  }
}

// ---------------------------------------------------------------------------
// kse: se[k] = ascending-c sequential fp32 chain of E[k][c]^2 (bit-faithful)
// ---------------------------------------------------------------------------
__global__ __launch_bounds__(256) void kse(float* __restrict__ out) {
  const int k = blockIdx.x * 256 + threadIdx.x;
  const float* Et = out + ET_OFF;
  float acc = 0.0f;
  #pragma unroll 8
  for (int c = 0; c < 256; c++) {
    float v = Et[c * 1024 + k];
    acc = __fadd_rn(acc, __fmul_rn(v, v));
  }
  out[k] = acc;
}

// ---------------------------------------------------------------------------
// kes: swizzled bf16 embedding in MFMA B-fragment order.
// e1s[tile][s][lane] (16B chunks): tile = code0/16 (0..63), s = 0..7,
// lane = 0..63 (r=lane&15, h=(lane>>4)&3).
// chunk = bf16(E[16*tile + r][8*h + 32*s + 0..7]).
// A wave's B-load for (tile,s) is 64 lanes x 16B = 1KB contiguous.
// ---------------------------------------------------------------------------
__global__ __launch_bounds__(256) void kes(const float* __restrict__ E,
                                           float* __restrict__ out) {
  unsigned short* e1s = (unsigned short*)(out + E1_OFF);
  const int tile = blockIdx.x;       // 0..63
  const int t = threadIdx.x;
  #pragma unroll
  for (int i = 0; i < 2; i++) {
    int chunk = t + 256 * i;         // 0..511
    int s = chunk >> 6, lane = chunk & 63;
    int r = lane & 15, h = (lane >> 4) & 3;
    const float* src = E + (16 * tile + r) * 256 + 8 * h + 32 * s;
    unsigned short o[8];
    #pragma unroll
    for (int j = 0; j < 8; j++) o[j] = bf16rne(src[j]);
    *(uint4*)(e1s + (size_t)tile * 4096 + (size_t)chunk * 8) = *(const uint4*)o;
  }
}

// ---------------------------------------------------------------------------
// kzt: zt[b][n][c] = bf16_rne(zz[c][n]).  n = w0*256 + m.  Row n holds 256
// contiguous bf16 channels -> A-frag loads are per-lane 16B contiguous.
// ---------------------------------------------------------------------------
__global__ __launch_bounds__(256) void kzt(const float* __restrict__ z,
                                           float* __restrict__ out) {
  __shared__ float tile[16][1028];   // 16 z-rows x 1024, pad 1028
  unsigned short* zt = (unsigned short*)(out + ZT_OFF);
  const int mg = blockIdx.x;         // 0..15 (16-row group)
  const int b  = blockIdx.y;         // 0..31
  const int t = threadIdx.x;
  #pragma unroll
  for (int i = 0; i < 16; i++) {     // row m=i, q=t: coalesced float4 loads
    float4 v = *(const float4*)(z + (size_t)b * 262144 + (size_t)(mg * 16 + i) * 1024 + 4 * t);
    *(float4*)&tile[i][4 * t] = v;
  }
  __syncthreads();
  const int m = t & 15, w0 = (t >> 4) & 3;   // R = t&63 spans (m,w0)
  const int n = w0 * 256 + mg * 16 + m;
  #pragma unroll
  for (int i = 0; i < 8; i++) {
    int g = 4 * i + (t >> 6);        // 0..31: 8-channel group
    int c0 = 8 * g;
    unsigned short o[8];
    #pragma unroll
    for (int j = 0; j < 8; j++)
      o[j] = bf16rne(tile[m][4 * (c0 + j) + w0]);
    *(uint4*)(zt + ((size_t)(b * 1024 + n)) * 256 + c0) = *(const uint4*)o;
  }
}

// ---------------------------------------------------------------------------
// kmain: MFMA approximate distances + provably-sound exact rescreen.
// R6 change: R5 ran the full GEMM TWICE (min phase + append phase) and was
// 70% latency-stalled (Mfma 11%, VALU 17%, no B prefetch at VGPR=92).
// Fix 1: SINGLE pass with one local candidate slot per (reg,half) — 16 hot
//   statically-indexed registers, never live across a barrier (no spill).
//   Insert when dd <= lmin+W; a still-valid old slot is SPILLED to the
//   shared list (rare; extras harmless — rescreen filters).  Eviction only
//   when old > lmin_new+W, which provably excludes final-window entries.
//   Per-Tp flush vs exact-final dmins[p]+W (each pixel's 1024 codes finish
//   within its Tp).  Soundness proof identical to R5: the exact winner k*
//   has dd(k*) <= gmin+W <= lmin_thread+W at scan time -> inserted-or-
//   spilled; never silently evicted; passes flush.  W=6e-3 >= 2*eps.
// Fix 2: explicit B double-buffer (Ba/Bb, 64 VGPR): the 8 loads for ti+1
//   issue before ti's MFMAs -> one full iteration of latency tolerance.
// ---------------------------------------------------------------------------
__global__ __launch_bounds__(256, 2) void kmain(const float* __restrict__ z,
                                                const float* __restrict__ E,
                                                float* __restrict__ out) {
  __shared__ __attribute__((aligned(16))) float VsT[256][65];  // exact z, [c][p]
  __shared__ __attribute__((aligned(16))) float szs[64];
  __shared__ __attribute__((aligned(16))) float dmins[64];
  __shared__ int   candK[64 * CAP];
  __shared__ float candD[64 * CAP];
  __shared__ int   cnt[64];

  const int t = threadIdx.x;
  const int ccg = blockIdx.x, b = blockIdx.y;
  const int cc0 = ccg * 16;
  const int lane = t & 63, w = t >> 6;
  const int r = t & 15, h = (t >> 4) & 3;
  const int w16r = w * 16 + r;
  const float* zb = z + (size_t)b * 262144;
  const float* se_g = out;
  const unsigned short* e1s = (const unsigned short*)(out + E1_OFF);
  const unsigned short* zt = (const unsigned short*)(out + ZT_OFF);

  if (t < 64) { cnt[t] = 0; dmins[t] = 3.4e38f; }

  // ---- stage VsT[c][p] = z[row cc0+i][4c+w0], p = 4i+w0 ----
  #pragma unroll
  for (int i = 0; i < 16; i++) {
    float4 v = *(const float4*)(zb + (cc0 + i) * 1024 + 4 * t);
    *(float4*)&VsT[t][4 * i] = v;
  }
  __syncthreads();

  // ---- sz: exact ascending-c chain; 16 px per wave (lanes 0-15) ----
  if (lane < 16) {
    const int p = w * 16 + lane;
    float a = 0.0f;
    #pragma unroll 8
    for (int c = 0; c < 256; c++)
      a = __fadd_rn(a, __fmul_rn(VsT[c][p], VsT[c][p]));
    szs[p] = a;
  }
  __syncthreads();

#define KBODY(TI, BCUR, BNXT)                                                 \
    {                                                                         \
      const int tin = ((TI) + 1) & 15;                                        \
      const unsigned short* bp =                                              \
          e1s + (size_t)(4 * tin + w) * 4096 + (size_t)lane * 8;              \
      _Pragma("unroll")                                                       \
      for (int s = 0; s < 8; s++) BNXT[s] = *(const v8s*)(bp + 512 * s);      \
      float se_n = se_g[tin * 64 + w16r];                                     \
      v4f acc0 = (v4f){0.f, 0.f, 0.f, 0.f};                                   \
      v4f acc1 = (v4f){0.f, 0.f, 0.f, 0.f};                                   \
      _Pragma("unroll")                                                       \
      for (int s = 0; s < 8; s++) {                                           \
        acc0 = __builtin_amdgcn_mfma_f32_16x16x32_bf16(A0[s], BCUR[s], acc0, 0, 0, 0); \
        acc1 = __builtin_amdgcn_mfma_f32_16x16x32_bf16(A1[s], BCUR[s], acc1, 0, 0, 0); \
      }                                                                       \
      const int kl = (TI) * 64 + w16r;                                        \
      _Pragma("unroll")                                                       \
      for (int reg = 0; reg < 4; reg++) {                                     \
        float dd0 = (se_c + sz0[reg]) - 2.0f * acc0[reg];                     \
        if (dd0 <= lm0[reg] + WWIN) {                                         \
          lm0[reg] = fminf(lm0[reg], dd0);                                    \
          if (sd0[reg] <= lm0[reg] + WWIN) {    /* old still valid: spill */  \
            int p = 16 * h + 4 * reg + T0;                                    \
            int o = atomicAdd(&cnt[p], 1);                                    \
            if (o < CAP) { candK[p*CAP+o] = sk0[reg]; candD[p*CAP+o] = sd0[reg]; } \
          }                                                                   \
          sd0[reg] = dd0; sk0[reg] = kl;                                      \
        }                                                                     \
        float dd1 = (se_c + sz1[reg]) - 2.0f * acc1[reg];                     \
        if (dd1 <= lm1[reg] + WWIN) {                                         \
          lm1[reg] = fminf(lm1[reg], dd1);                                    \
          if (sd1[reg] <= lm1[reg] + WWIN) {                                  \
            int p = 16 * h + 4 * reg + T1;                                    \
            int o = atomicAdd(&cnt[p], 1);                                    \
            if (o < CAP) { candK[p*CAP+o] = sk1[reg]; candD[p*CAP+o] = sd1[reg]; } \
          }                                                                   \
          sd1[reg] = dd1; sk1[reg] = kl;                                      \
        }                                                                     \
      }                                                                       \
      se_c = se_n;                                                            \
    }

  #pragma unroll 1
  for (int Tp = 0; Tp < 2; Tp++) {
    const int T0 = 2 * Tp, T1 = T0 + 1;
    // A-frags: 16 contiguous 16B loads from zt (rows T0*256.., T1*256..)
    v8s A0[8], A1[8];
    {
      const unsigned short* a0p =
          zt + ((size_t)(b * 1024 + T0 * 256 + cc0 + r)) * 256 + 8 * h;
      const unsigned short* a1p = a0p + 256 * 256;   // T1 = T0+1
      #pragma unroll
      for (int s = 0; s < 8; s++) {
        A0[s] = *(const v8s*)(a0p + 32 * s);
        A1[s] = *(const v8s*)(a1p + 32 * s);
      }
    }
    float sz0[4], sz1[4], lm0[4], lm1[4], sd0[4], sd1[4];
    int sk0[4], sk1[4];
    #pragma unroll
    for (int reg = 0; reg < 4; reg++) {
      sz0[reg] = szs[16 * h + 4 * reg + T0];
      sz1[reg] = szs[16 * h + 4 * reg + T1];
      lm0[reg] = 3.4e38f; lm1[reg] = 3.4e38f;
      sd0[reg] = 3.4e38f; sd1[reg] = 3.4e38f;
      sk0[reg] = 0; sk1[reg] = 0;
    }

    // B double-buffer: preload ti=0, then compute(cur) || prefetch(next)
    v8s Ba[8], Bb[8];
    {
      const unsigned short* bp = e1s + (size_t)w * 4096 + (size_t)lane * 8;
      #pragma unroll
      for (int s = 0; s < 8; s++) Ba[s] = *(const v8s*)(bp + 512 * s);
    }
    float se_c = se_g[w16r];

    #pragma unroll
    for (int td = 0; td < 8; td++) {
      KBODY(2 * td, Ba, Bb);
      KBODY(2 * td + 1, Bb, Ba);
    }

    // ---- finalize this Tp's pixels: exact-final min, then flush slots ----
    #pragma unroll
    for (int reg = 0; reg < 4; reg++) {
      atomicMin((int*)&dmins[16 * h + 4 * reg + T0], __float_as_int(lm0[reg]));
      atomicMin((int*)&dmins[16 * h + 4 * reg + T1], __float_as_int(lm1[reg]));
    }
    __syncthreads();
    #pragma unroll
    for (int reg = 0; reg < 4; reg++) {
      {
        int p = 16 * h + 4 * reg + T0;
        if (sd0[reg] <= dmins[p] + WWIN) {
          int o = atomicAdd(&cnt[p], 1);
          if (o < CAP) { candK[p * CAP + o] = sk0[reg]; candD[p * CAP + o] = sd0[reg]; }
        }
      }
      {
        int p = 16 * h + 4 * reg + T1;
        if (sd1[reg] <= dmins[p] + WWIN) {
          int o = atomicAdd(&cnt[p], 1);
          if (o < CAP) { candK[p * CAP + o] = sk1[reg]; candD[p * CAP + o] = sd1[reg]; }
        }
      }
    }
  }
#undef KBODY
  __syncthreads();   // all appends visible

  // ---- exact rescreen: bit-identical fp32 chain for surviving candidates ----
  for (int i = t; i < 64 * CAP; i += 256) {
    int p = i / CAP, slot = i - p * CAP;
    int cn = cnt[p];
    if (cn > CAP || slot >= cn) continue;     // overflow px -> fallback
    int k = candK[i];
    const float* er = E + (size_t)k * 256;
    float dot = 0.0f;
    #pragma unroll 8
    for (int c = 0; c < 256; c++)
      dot = __fmaf_rn(VsT[c][p], er[c], dot);
    candD[i] = __fsub_rn(__fadd_rn(se_g[k], szs[p]), __fmul_rn(2.0f, dot));
  }
  __syncthreads();

  // ---- winners: lexicographic (d,k) min == first-index argmin ----
  if (t < 64) {
    int p = t, cn = cnt[p];
    if (cn <= CAP) {
      float bd = 3.4e38f; int bi = 0x7FFFFFFF;
      for (int s2 = 0; s2 < cn; s2++) {
        float d2 = candD[p * CAP + s2]; int k2 = candK[p * CAP + s2];
        if (d2 < bd || (d2 == bd && k2 < bi)) { bd = d2; bi = k2; }
      }
      int rr = p >> 2, w0 = p & 3;
      out[IDX_OFF + b * 1024 + (w0 * 256 + cc0 + rr)] = (float)bi;
    }
  }

  // ---- fallback: overflowed px -> exact full scan by one wave (dead code
  // in practice: exact-final flush threshold + rare spills; P(>24) ~ 0) ----
  for (int p = 0; p < 64; p++) {
    if (cnt[p] > CAP && (p & 3) == w) {
      float bd = 3.4e38f; int bi = 0x7FFFFFFF;
      for (int k = lane; k < 1024; k += 64) {
        const float* er = E + (size_t)k * 256;
        float dot = 0.0f;
        #pragma unroll 8
        for (int c = 0; c < 256; c++)
          dot = __fmaf_rn(VsT[c][p], er[c], dot);
        float d2 = __fsub_rn(__fadd_rn(se_g[k], szs[p]), __fmul_rn(2.0f, dot));
        if (d2 < bd || (d2 == bd && k < bi)) { bd = d2; bi = k; }
      }
      #pragma unroll
      for (int mm = 32; mm >= 1; mm >>= 1) {
        float d2 = __shfl_xor(bd, mm, 64);
        int i2 = __shfl_xor(bi, mm, 64);
        if (d2 < bd || (d2 == bd && i2 < bi)) { bd = d2; bi = i2; }
      }
      if (lane == 0) {
        int rr = p >> 2, w0 = p & 3;
        out[IDX_OFF + b * 1024 + (w0 * 256 + cc0 + rr)] = (float)bi;
      }
    }
  }
}

// ---------------------------------------------------------------------------
// kout: z_q_st = fl(zp + fl(zq - zp)); per-block loss partial -> d_ws
// ---------------------------------------------------------------------------
__global__ __launch_bounds__(256) void kout(const float* __restrict__ z,
                                            const float* __restrict__ E,
                                            float* __restrict__ out,
                                            float* __restrict__ ws) {
  __shared__ float red[4];
  const int t = threadIdx.x;
  const size_t g4 = (size_t)blockIdx.x * 256 + t;
  const size_t g = g4 * 4;
  const int b = (int)(g >> 18);
  const int c = (int)((g >> 10) & 255);
  const int n = (int)(g & 1023);

  float4 zp = *(const float4*)(z + g);
  float4 idxf = *(const float4*)(out + IDX_OFF + b * 1024 + n);
  int i0 = (int)idxf.x, i1 = (int)idxf.y, i2 = (int)idxf.z, i3 = (int)idxf.w;
  float q0 = E[i0 * 256 + c];
  float q1 = E[i1 * 256 + c];
  float q2 = E[i2 * 256 + c];
  float q3 = E[i3 * 256 + c];
  float d0 = __fsub_rn(q0, zp.x);
  float d1 = __fsub_rn(q1, zp.y);
  float d2 = __fsub_rn(q2, zp.z);
  float d3 = __fsub_rn(q3, zp.w);
  float4 o;
  o.x = __fadd_rn(zp.x, d0);
  o.y = __fadd_rn(zp.y, d1);
  o.z = __fadd_rn(zp.z, d2);
  o.w = __fadd_rn(zp.w, d3);
  *(float4*)(out + g) = o;

  float s = d0 * d0 + d1 * d1 + d2 * d2 + d3 * d3;
  #pragma unroll
  for (int off = 32; off > 0; off >>= 1) s += __shfl_down(s, off);
  if ((t & 63) == 0) red[t >> 6] = s;
  __syncthreads();
  if (t == 0) ws[blockIdx.x] = red[0] + red[1] + red[2] + red[3];
}

// ---------------------------------------------------------------------------
// kfin: loss = 1.25 * (sum(ws)/N)
// ---------------------------------------------------------------------------
__global__ __launch_bounds__(256) void kfin(const float* __restrict__ ws,
                                            float* __restrict__ out) {
  __shared__ float red[4];
  const int t = threadIdx.x;
  float s = 0.0f;
  #pragma unroll
  for (int i = 0; i < 32; i++) s += ws[t + 256 * i];
  #pragma unroll
  for (int off = 32; off > 0; off >>= 1) s += __shfl_down(s, off);
  if ((t & 63) == 0) red[t >> 6] = s;
  __syncthreads();
  if (t == 0) {
    float S = red[0] + red[1] + red[2] + red[3];
    float m = S / 8388608.0f;
    out[LOSS_OFF] = __fadd_rn(m, __fmul_rn(0.25f, m));
  }
}

extern "C" void kernel_launch(void* const* d_in, const int* in_sizes, int n_in,
                              void* d_out, int out_size, void* d_ws, size_t ws_size,
                              hipStream_t stream) {
  const float* z = (const float*)d_in[0];    // [32,256,32,32]
  const float* E = (const float*)d_in[1];    // [1024,256]
  float* out = (float*)d_out;
  float* ws = (float*)d_ws;

  ktr<<<dim3(16, 4), 256, 0, stream>>>(E, out);
  kse<<<dim3(4), 256, 0, stream>>>(out);
  kes<<<dim3(64), 256, 0, stream>>>(E, out);
  kzt<<<dim3(16, 32), 256, 0, stream>>>(z, out);
  kmain<<<dim3(16, 32), 256, 0, stream>>>(z, E, out);
  kout<<<dim3(8192), 256, 0, stream>>>(z, E, out, ws);
  kfin<<<dim3(1), 256, 0, stream>>>(ws, out);
}

// Round 7
// 458.326 us; speedup vs baseline: 8.2578x; 8.2578x over previous
//
#include <hip/hip_runtime.h>
#include <stdint.h>

// Problem constants
#define ZSIZE   8388608      // 32*256*32*32
#define NPIX    32768        // 32*32*32
#define IDX_OFF ZSIZE        // idx output offset (floats) in d_out
#define LOSS_OFF (ZSIZE + NPIX)
#define ET_OFF  1024         // Et fp32 [256][1024] scratch (for kse)
#define E1_OFF  263168       // e1s swizzled bf16 (131072 floats = 512 KB)
#define ZT_OFF  394240       // zt bf16 [32][1024][256] (4194304 floats)
#define CAP     24           // candidate slots per pixel
#define WWIN    6.0e-3f      // window >= 2*eps_bound (eps<=2.4e-3 rigorous)

using v8s = __attribute__((ext_vector_type(8))) short;   // 8 bf16 (4 VGPR)
using v4f = __attribute__((ext_vector_type(4))) float;   // MFMA acc

__device__ __forceinline__ unsigned short bf16rne(float f) {
  unsigned u = __float_as_uint(f);
  return (unsigned short)((u + 0x7FFFu + ((u >> 16) & 1u)) >> 16);
}

// ---------------------------------------------------------------------------
// ktr: transpose embedding E[1024][256] -> Et[256][1024] (feeds kse only)
// ---------------------------------------------------------------------------
__global__ __launch_bounds__(256) void ktr(const float* __restrict__ E,
                                           float* __restrict__ out) {
  __shared__ float tile[64][65];
  const int k0 = blockIdx.x * 64;
  const int c0 = blockIdx.y * 64;
  const int t = threadIdx.x;
  #pragma unroll
  for (int i = 0; i < 4; i++) {
    int f = t + 256 * i;
    int r = f >> 4, q = f & 15;
    float4 e = *(const float4*)(E + (k0 + r) * 256 + c0 + 4 * q);
    tile[r][4 * q + 0] = e.x; tile[r][4 * q + 1] = e.y;
    tile[r][4 * q + 2] = e.z; tile[r][4 * q + 3] = e.w;
  }
  __syncthreads();
  #pragma unroll
  for (int i = 0; i < 4; i++) {
    int f = t + 256 * i;
    int cr = f >> 4, kq = f & 15;
    float4 o;
    o.x = tile[4 * kq + 0][cr];
    o.y = tile[4 * kq + 1][cr];
    o.z = tile[4 * kq + 2][cr];
    o.w = tile[4 * kq + 3][cr];
    *(float4*)(out + ET_OFF + (c0 + cr) * 1024 + k0 + 4 * kq) = o;
  }
}

// ---------------------------------------------------------------------------
// kse: se[k] = ascending-c sequential fp32 chain of E[k][c]^2 (bit-faithful)
// ---------------------------------------------------------------------------
__global__ __launch_bounds__(256) void kse(float* __restrict__ out) {
  const int k = blockIdx.x * 256 + threadIdx.x;
  const float* Et = out + ET_OFF;
  float acc = 0.0f;
  #pragma unroll 8
  for (int c = 0; c < 256; c++) {
    float v = Et[c * 1024 + k];
    acc = __fadd_rn(acc, __fmul_rn(v, v));
  }
  out[k] = acc;
}

// ---------------------------------------------------------------------------
// kes: swizzled bf16 embedding in MFMA B-fragment order.
// e1s[tile][s][lane] (16B chunks): tile = code0/16 (0..63), s = 0..7,
// lane = 0..63 (r=lane&15, h=(lane>>4)&3).
// chunk = bf16(E[16*tile + r][8*h + 32*s + 0..7]).
// A wave's B-load for (tile,s) is 64 lanes x 16B = 1KB contiguous.
// ---------------------------------------------------------------------------
__global__ __launch_bounds__(256) void kes(const float* __restrict__ E,
                                           float* __restrict__ out) {
  unsigned short* e1s = (unsigned short*)(out + E1_OFF);
  const int tile = blockIdx.x;       // 0..63
  const int t = threadIdx.x;
  #pragma unroll
  for (int i = 0; i < 2; i++) {
    int chunk = t + 256 * i;         // 0..511
    int s = chunk >> 6, lane = chunk & 63;
    int r = lane & 15, h = (lane >> 4) & 3;
    const float* src = E + (16 * tile + r) * 256 + 8 * h + 32 * s;
    unsigned short o[8];
    #pragma unroll
    for (int j = 0; j < 8; j++) o[j] = bf16rne(src[j]);
    *(uint4*)(e1s + (size_t)tile * 4096 + (size_t)chunk * 8) = *(const uint4*)o;
  }
}

// ---------------------------------------------------------------------------
// kzt: zt[b][n][c] = bf16_rne(zz[c][n]).  n = w0*256 + m.  Row n holds 256
// contiguous bf16 channels -> A-frag loads are per-lane 16B contiguous.
// ---------------------------------------------------------------------------
__global__ __launch_bounds__(256) void kzt(const float* __restrict__ z,
                                           float* __restrict__ out) {
  __shared__ float tile[16][1028];   // 16 z-rows x 1024, pad 1028
  unsigned short* zt = (unsigned short*)(out + ZT_OFF);
  const int mg = blockIdx.x;         // 0..15 (16-row group)
  const int b  = blockIdx.y;         // 0..31
  const int t = threadIdx.x;
  #pragma unroll
  for (int i = 0; i < 16; i++) {     // row m=i, q=t: coalesced float4 loads
    float4 v = *(const float4*)(z + (size_t)b * 262144 + (size_t)(mg * 16 + i) * 1024 + 4 * t);
    *(float4*)&tile[i][4 * t] = v;
  }
  __syncthreads();
  const int m = t & 15, w0 = (t >> 4) & 3;   // R = t&63 spans (m,w0)
  const int n = w0 * 256 + mg * 16 + m;
  #pragma unroll
  for (int i = 0; i < 8; i++) {
    int g = 4 * i + (t >> 6);        // 0..31: 8-channel group
    int c0 = 8 * g;
    unsigned short o[8];
    #pragma unroll
    for (int j = 0; j < 8; j++)
      o[j] = bf16rne(tile[m][4 * (c0 + j) + w0]);
    *(uint4*)(zt + ((size_t)(b * 1024 + n)) * 256 + c0) = *(const uint4*)o;
  }
}

// ---------------------------------------------------------------------------
// kmain: MFMA approximate distances + provably-sound exact rescreen.
// R7 = R5 structure (proven: 120us, VGPR 92, no spill) + explicit B
// double-buffer.  R6's single-pass slot machinery re-spilled (VGPR 128,
// WRITE 96MB, 3.7ms) — reverted.  R5's stall arithmetic: loads awaited
// immediately by the MFMA block (no prefetch kept at VGPR 92); per-SIMD
// MFMA work ~160cy vs ~250-300cy L2 latency -> 70% idle (MfmaUtil 11%).
// Dbuf: ti+1's 8 B-loads issue BEFORE ti's MFMAs -> wait lands one full
// iteration later, covered by 16 MFMAs + 8 load-issues x 2 waves/SIMD.
// Live set A0/A1(64)+Ba/Bb(64)+acc(8)+scalars(~25) ~ 165 < 256 available
// at the LDS-capped 2 blocks/CU.  Phase 1 stays BRANCHLESS (fminf only);
// phase 2 keeps R5's append shape.  Numerics bit-identical to R5
// (same loads, same MFMA order, same dd chain) -> absmax stays 0.
// Spill canary: WRITE_SIZE must stay ~128KB.
// ---------------------------------------------------------------------------
__global__ __launch_bounds__(256, 2) void kmain(const float* __restrict__ z,
                                                const float* __restrict__ E,
                                                float* __restrict__ out) {
  __shared__ __attribute__((aligned(16))) float VsT[256][65];  // exact z, [c][p]
  __shared__ __attribute__((aligned(16))) float szs[64];
  __shared__ __attribute__((aligned(16))) float dmins[64];
  __shared__ int   candK[64 * CAP];
  __shared__ float candD[64 * CAP];
  __shared__ int   cnt[64];

  const int t = threadIdx.x;
  const int ccg = blockIdx.x, b = blockIdx.y;
  const int cc0 = ccg * 16;
  const int lane = t & 63, w = t >> 6;
  const int r = t & 15, h = (t >> 4) & 3;
  const int w16r = w * 16 + r;
  const float* zb = z + (size_t)b * 262144;
  const float* se_g = out;
  const unsigned short* e1s = (const unsigned short*)(out + E1_OFF);
  const unsigned short* zt = (const unsigned short*)(out + ZT_OFF);

  if (t < 64) { cnt[t] = 0; dmins[t] = 3.4e38f; }

  // ---- stage VsT[c][p] = z[row cc0+i][4c+w0], p = 4i+w0 ----
  #pragma unroll
  for (int i = 0; i < 16; i++) {
    float4 v = *(const float4*)(zb + (cc0 + i) * 1024 + 4 * t);
    *(float4*)&VsT[t][4 * i] = v;
  }
  __syncthreads();

  // ---- sz: exact ascending-c chain; 16 px per wave (lanes 0-15) ----
  if (lane < 16) {
    const int p = w * 16 + lane;
    float a = 0.0f;
    #pragma unroll 8
    for (int c = 0; c < 256; c++)
      a = __fadd_rn(a, __fmul_rn(VsT[c][p], VsT[c][p]));
    szs[p] = a;
  }
  __syncthreads();

  // B prefetch macro: load tile (4*TIN + w) into BDST
#define BPREF(TIN, BDST)                                                      \
    {                                                                         \
      const unsigned short* bp =                                              \
          e1s + (size_t)(4 * ((TIN) & 15) + w) * 4096 + (size_t)lane * 8;     \
      _Pragma("unroll")                                                       \
      for (int s = 0; s < 8; s++) BDST[s] = *(const v8s*)(bp + 512 * s);      \
    }

  // ======== phase 1: min scan (branchless; B double-buffered) ========
  #pragma unroll 1
  for (int Tp = 0; Tp < 2; Tp++) {
    const int T0 = 2 * Tp, T1 = T0 + 1;
    v8s A0[8], A1[8];
    {
      const unsigned short* a0p =
          zt + ((size_t)(b * 1024 + T0 * 256 + cc0 + r)) * 256 + 8 * h;
      const unsigned short* a1p = a0p + 256 * 256;   // T1 = T0+1
      #pragma unroll
      for (int s = 0; s < 8; s++) {
        A0[s] = *(const v8s*)(a0p + 32 * s);
        A1[s] = *(const v8s*)(a1p + 32 * s);
      }
    }
    float sz0[4], sz1[4], b0[4], b1[4];
    #pragma unroll
    for (int reg = 0; reg < 4; reg++) {
      sz0[reg] = szs[16 * h + 4 * reg + T0];
      sz1[reg] = szs[16 * h + 4 * reg + T1];
      b0[reg] = 3.4e38f; b1[reg] = 3.4e38f;
    }

    v8s Ba[8], Bb[8];
    BPREF(0, Ba);

#define P1BODY(TI, BCUR, BNXT)                                                \
    {                                                                         \
      BPREF((TI) + 1, BNXT);                                                  \
      v4f acc0 = (v4f){0.f, 0.f, 0.f, 0.f};                                   \
      v4f acc1 = (v4f){0.f, 0.f, 0.f, 0.f};                                   \
      _Pragma("unroll")                                                       \
      for (int s = 0; s < 8; s++) {                                           \
        acc0 = __builtin_amdgcn_mfma_f32_16x16x32_bf16(A0[s], BCUR[s], acc0, 0, 0, 0); \
        acc1 = __builtin_amdgcn_mfma_f32_16x16x32_bf16(A1[s], BCUR[s], acc1, 0, 0, 0); \
      }                                                                       \
      float se_l = se_g[(TI) * 64 + w16r];                                    \
      _Pragma("unroll")                                                       \
      for (int reg = 0; reg < 4; reg++) {                                     \
        b0[reg] = fminf(b0[reg], (se_l + sz0[reg]) - 2.0f * acc0[reg]);       \
        b1[reg] = fminf(b1[reg], (se_l + sz1[reg]) - 2.0f * acc1[reg]);       \
      }                                                                       \
    }

    #pragma unroll
    for (int td = 0; td < 8; td++) {
      P1BODY(2 * td, Ba, Bb);
      P1BODY(2 * td + 1, Bb, Ba);
    }
#undef P1BODY

    #pragma unroll
    for (int reg = 0; reg < 4; reg++) {
      atomicMin((int*)&dmins[16 * h + 4 * reg + T0], __float_as_int(b0[reg]));
      atomicMin((int*)&dmins[16 * h + 4 * reg + T1], __float_as_int(b1[reg]));
    }
  }
  __syncthreads();   // dmins exact-final

  // ======== phase 2: recompute dd, append dd <= dmin + W ========
  #pragma unroll 1
  for (int Tp = 0; Tp < 2; Tp++) {
    const int T0 = 2 * Tp, T1 = T0 + 1;
    v8s A0[8], A1[8];
    {
      const unsigned short* a0p =
          zt + ((size_t)(b * 1024 + T0 * 256 + cc0 + r)) * 256 + 8 * h;
      const unsigned short* a1p = a0p + 256 * 256;
      #pragma unroll
      for (int s = 0; s < 8; s++) {
        A0[s] = *(const v8s*)(a0p + 32 * s);
        A1[s] = *(const v8s*)(a1p + 32 * s);
      }
    }
    float sz0[4], sz1[4], th0[4], th1[4];
    #pragma unroll
    for (int reg = 0; reg < 4; reg++) {
      sz0[reg] = szs[16 * h + 4 * reg + T0];
      sz1[reg] = szs[16 * h + 4 * reg + T1];
      th0[reg] = dmins[16 * h + 4 * reg + T0] + WWIN;
      th1[reg] = dmins[16 * h + 4 * reg + T1] + WWIN;
    }

    v8s Ba[8], Bb[8];
    BPREF(0, Ba);

#define P2BODY(TI, BCUR, BNXT)                                                \
    {                                                                         \
      BPREF((TI) + 1, BNXT);                                                  \
      v4f acc0 = (v4f){0.f, 0.f, 0.f, 0.f};                                   \
      v4f acc1 = (v4f){0.f, 0.f, 0.f, 0.f};                                   \
      _Pragma("unroll")                                                       \
      for (int s = 0; s < 8; s++) {                                           \
        acc0 = __builtin_amdgcn_mfma_f32_16x16x32_bf16(A0[s], BCUR[s], acc0, 0, 0, 0); \
        acc1 = __builtin_amdgcn_mfma_f32_16x16x32_bf16(A1[s], BCUR[s], acc1, 0, 0, 0); \
      }                                                                       \
      float se_l = se_g[(TI) * 64 + w16r];                                    \
      const int kl = (TI) * 64 + w16r;                                        \
      _Pragma("unroll")                                                       \
      for (int reg = 0; reg < 4; reg++) {                                     \
        float dd0 = (se_l + sz0[reg]) - 2.0f * acc0[reg];                     \
        if (dd0 <= th0[reg]) {                                                \
          int p = 16 * h + 4 * reg + T0;                                      \
          int o = atomicAdd(&cnt[p], 1);                                      \
          if (o < CAP) { candK[p*CAP+o] = kl; candD[p*CAP+o] = dd0; }         \
        }                                                                     \
        float dd1 = (se_l + sz1[reg]) - 2.0f * acc1[reg];                     \
        if (dd1 <= th1[reg]) {                                                \
          int p = 16 * h + 4 * reg + T1;                                      \
          int o = atomicAdd(&cnt[p], 1);                                      \
          if (o < CAP) { candK[p*CAP+o] = kl; candD[p*CAP+o] = dd1; }         \
        }                                                                     \
      }                                                                       \
    }

    #pragma unroll
    for (int td = 0; td < 8; td++) {
      P2BODY(2 * td, Ba, Bb);
      P2BODY(2 * td + 1, Bb, Ba);
    }
#undef P2BODY
  }
#undef BPREF
  __syncthreads();   // all appends visible

  // ---- exact rescreen: bit-identical fp32 chain for surviving candidates ----
  for (int i = t; i < 64 * CAP; i += 256) {
    int p = i / CAP, slot = i - p * CAP;
    int cn = cnt[p];
    if (cn > CAP || slot >= cn) continue;     // overflow px -> fallback
    int k = candK[i];
    const float* er = E + (size_t)k * 256;
    float dot = 0.0f;
    #pragma unroll 8
    for (int c = 0; c < 256; c++)
      dot = __fmaf_rn(VsT[c][p], er[c], dot);
    candD[i] = __fsub_rn(__fadd_rn(se_g[k], szs[p]), __fmul_rn(2.0f, dot));
  }
  __syncthreads();

  // ---- winners: lexicographic (d,k) min == first-index argmin ----
  if (t < 64) {
    int p = t, cn = cnt[p];
    if (cn <= CAP) {
      float bd = 3.4e38f; int bi = 0x7FFFFFFF;
      for (int s2 = 0; s2 < cn; s2++) {
        float d2 = candD[p * CAP + s2]; int k2 = candK[p * CAP + s2];
        if (d2 < bd || (d2 == bd && k2 < bi)) { bd = d2; bi = k2; }
      }
      int rr = p >> 2, w0 = p & 3;
      out[IDX_OFF + b * 1024 + (w0 * 256 + cc0 + rr)] = (float)bi;
    }
  }

  // ---- fallback: overflowed px -> exact full scan by one wave (dead code
  // in practice: exact-final threshold, lambda ~ 3/px, P(>24) ~ 1e-12) ----
  for (int p = 0; p < 64; p++) {
    if (cnt[p] > CAP && (p & 3) == w) {
      float bd = 3.4e38f; int bi = 0x7FFFFFFF;
      for (int k = lane; k < 1024; k += 64) {
        const float* er = E + (size_t)k * 256;
        float dot = 0.0f;
        #pragma unroll 8
        for (int c = 0; c < 256; c++)
          dot = __fmaf_rn(VsT[c][p], er[c], dot);
        float d2 = __fsub_rn(__fadd_rn(se_g[k], szs[p]), __fmul_rn(2.0f, dot));
        if (d2 < bd || (d2 == bd && k < bi)) { bd = d2; bi = k; }
      }
      #pragma unroll
      for (int mm = 32; mm >= 1; mm >>= 1) {
        float d2 = __shfl_xor(bd, mm, 64);
        int i2 = __shfl_xor(bi, mm, 64);
        if (d2 < bd || (d2 == bd && i2 < bi)) { bd = d2; bi = i2; }
      }
      if (lane == 0) {
        int rr = p >> 2, w0 = p & 3;
        out[IDX_OFF + b * 1024 + (w0 * 256 + cc0 + rr)] = (float)bi;
      }
    }
  }
}

// ---------------------------------------------------------------------------
// kout: z_q_st = fl(zp + fl(zq - zp)); per-block loss partial -> d_ws
// ---------------------------------------------------------------------------
__global__ __launch_bounds__(256) void kout(const float* __restrict__ z,
                                            const float* __restrict__ E,
                                            float* __restrict__ out,
                                            float* __restrict__ ws) {
  __shared__ float red[4];
  const int t = threadIdx.x;
  const size_t g4 = (size_t)blockIdx.x * 256 + t;
  const size_t g = g4 * 4;
  const int b = (int)(g >> 18);
  const int c = (int)((g >> 10) & 255);
  const int n = (int)(g & 1023);

  float4 zp = *(const float4*)(z + g);
  float4 idxf = *(const float4*)(out + IDX_OFF + b * 1024 + n);
  int i0 = (int)idxf.x, i1 = (int)idxf.y, i2 = (int)idxf.z, i3 = (int)idxf.w;
  float q0 = E[i0 * 256 + c];
  float q1 = E[i1 * 256 + c];
  float q2 = E[i2 * 256 + c];
  float q3 = E[i3 * 256 + c];
  float d0 = __fsub_rn(q0, zp.x);
  float d1 = __fsub_rn(q1, zp.y);
  float d2 = __fsub_rn(q2, zp.z);
  float d3 = __fsub_rn(q3, zp.w);
  float4 o;
  o.x = __fadd_rn(zp.x, d0);
  o.y = __fadd_rn(zp.y, d1);
  o.z = __fadd_rn(zp.z, d2);
  o.w = __fadd_rn(zp.w, d3);
  *(float4*)(out + g) = o;

  float s = d0 * d0 + d1 * d1 + d2 * d2 + d3 * d3;
  #pragma unroll
  for (int off = 32; off > 0; off >>= 1) s += __shfl_down(s, off);
  if ((t & 63) == 0) red[t >> 6] = s;
  __syncthreads();
  if (t == 0) ws[blockIdx.x] = red[0] + red[1] + red[2] + red[3];
}

// ---------------------------------------------------------------------------
// kfin: loss = 1.25 * (sum(ws)/N)
// ---------------------------------------------------------------------------
__global__ __launch_bounds__(256) void kfin(const float* __restrict__ ws,
                                            float* __restrict__ out) {
  __shared__ float red[4];
  const int t = threadIdx.x;
  float s = 0.0f;
  #pragma unroll
  for (int i = 0; i < 32; i++) s += ws[t + 256 * i];
  #pragma unroll
  for (int off = 32; off > 0; off >>= 1) s += __shfl_down(s, off);
  if ((t & 63) == 0) red[t >> 6] = s;
  __syncthreads();
  if (t == 0) {
    float S = red[0] + red[1] + red[2] + red[3];
    float m = S / 8388608.0f;
    out[LOSS_OFF] = __fadd_rn(m, __fmul_rn(0.25f, m));
  }
}

extern "C" void kernel_launch(void* const* d_in, const int* in_sizes, int n_in,
                              void* d_out, int out_size, void* d_ws, size_t ws_size,
                              hipStream_t stream) {
  const float* z = (const float*)d_in[0];    // [32,256,32,32]
  const float* E = (const float*)d_in[1];    // [1024,256]
  float* out = (float*)d_out;
  float* ws = (float*)d_ws;

  ktr<<<dim3(16, 4), 256, 0, stream>>>(E, out);
  kse<<<dim3(4), 256, 0, stream>>>(out);
  kes<<<dim3(64), 256, 0, stream>>>(E, out);
  kzt<<<dim3(16, 32), 256, 0, stream>>>(z, out);
  kmain<<<dim3(16, 32), 256, 0, stream>>>(z, E, out);
  kout<<<dim3(8192), 256, 0, stream>>>(z, E, out, ws);
  kfin<<<dim3(1), 256, 0, stream>>>(ws, out);
}

// Round 8
// 426.050 us; speedup vs baseline: 8.8834x; 1.0758x over previous
//
#include <hip/hip_runtime.h>
#include <stdint.h>

// Problem constants
#define ZSIZE   8388608      // 32*256*32*32
#define NPIX    32768        // 32*32*32
#define IDX_OFF ZSIZE        // idx output offset (floats) in d_out
#define LOSS_OFF (ZSIZE + NPIX)
#define ET_OFF  1024         // Et fp32 [256][1024] scratch (for kse)
#define E1_OFF  263168       // e1s swizzled bf16 (131072 floats = 512 KB)
#define ZT_OFF  394240       // zt bf16 [32][1024][256] (4194304 floats)
#define CAP     24           // candidate slots per pixel
#define WWIN    6.0e-3f      // window >= 2*eps_bound (eps<=2.4e-3 rigorous)

using v8s = __attribute__((ext_vector_type(8))) short;   // 8 bf16 (4 VGPR)
using v4f = __attribute__((ext_vector_type(4))) float;   // MFMA acc

__device__ __forceinline__ unsigned short bf16rne(float f) {
  unsigned u = __float_as_uint(f);
  return (unsigned short)((u + 0x7FFFu + ((u >> 16) & 1u)) >> 16);
}

// ---------------------------------------------------------------------------
// ktr: transpose embedding E[1024][256] -> Et[256][1024] (feeds kse only)
// ---------------------------------------------------------------------------
__global__ __launch_bounds__(256) void ktr(const float* __restrict__ E,
                                           float* __restrict__ out) {
  __shared__ float tile[64][65];
  const int k0 = blockIdx.x * 64;
  const int c0 = blockIdx.y * 64;
  const int t = threadIdx.x;
  #pragma unroll
  for (int i = 0; i < 4; i++) {
    int f = t + 256 * i;
    int r = f >> 4, q = f & 15;
    float4 e = *(const float4*)(E + (k0 + r) * 256 + c0 + 4 * q);
    tile[r][4 * q + 0] = e.x; tile[r][4 * q + 1] = e.y;
    tile[r][4 * q + 2] = e.z; tile[r][4 * q + 3] = e.w;
  }
  __syncthreads();
  #pragma unroll
  for (int i = 0; i < 4; i++) {
    int f = t + 256 * i;
    int cr = f >> 4, kq = f & 15;
    float4 o;
    o.x = tile[4 * kq + 0][cr];
    o.y = tile[4 * kq + 1][cr];
    o.z = tile[4 * kq + 2][cr];
    o.w = tile[4 * kq + 3][cr];
    *(float4*)(out + ET_OFF + (c0 + cr) * 1024 + k0 + 4 * kq) = o;
  }
}

// ---------------------------------------------------------------------------
// kse: se[k] = ascending-c sequential fp32 chain of E[k][c]^2 (bit-faithful)
// ---------------------------------------------------------------------------
__global__ __launch_bounds__(256) void kse(float* __restrict__ out) {
  const int k = blockIdx.x * 256 + threadIdx.x;
  const float* Et = out + ET_OFF;
  float acc = 0.0f;
  #pragma unroll 8
  for (int c = 0; c < 256; c++) {
    float v = Et[c * 1024 + k];
    acc = __fadd_rn(acc, __fmul_rn(v, v));
  }
  out[k] = acc;
}

// ---------------------------------------------------------------------------
// kes: swizzled bf16 embedding in MFMA B-fragment order.
// e1s[tile][s][lane] (16B chunks): tile = code0/16 (0..63), s = 0..7,
// lane = 0..63 (r=lane&15, h=(lane>>4)&3).
// chunk = bf16(E[16*tile + r][8*h + 32*s + 0..7]).
// A wave's B-load for (tile,s) is 64 lanes x 16B = 1KB contiguous.
// ---------------------------------------------------------------------------
__global__ __launch_bounds__(256) void kes(const float* __restrict__ E,
                                           float* __restrict__ out) {
  unsigned short* e1s = (unsigned short*)(out + E1_OFF);
  const int tile = blockIdx.x;       // 0..63
  const int t = threadIdx.x;
  #pragma unroll
  for (int i = 0; i < 2; i++) {
    int chunk = t + 256 * i;         // 0..511
    int s = chunk >> 6, lane = chunk & 63;
    int r = lane & 15, h = (lane >> 4) & 3;
    const float* src = E + (16 * tile + r) * 256 + 8 * h + 32 * s;
    unsigned short o[8];
    #pragma unroll
    for (int j = 0; j < 8; j++) o[j] = bf16rne(src[j]);
    *(uint4*)(e1s + (size_t)tile * 4096 + (size_t)chunk * 8) = *(const uint4*)o;
  }
}

// ---------------------------------------------------------------------------
// kzt: zt[b][n][c] = bf16_rne(zz[c][n]).  n = w0*256 + m.  Row n holds 256
// contiguous bf16 channels -> A-frag loads are per-lane 16B contiguous.
// ---------------------------------------------------------------------------
__global__ __launch_bounds__(256) void kzt(const float* __restrict__ z,
                                           float* __restrict__ out) {
  __shared__ float tile[16][1028];   // 16 z-rows x 1024, pad 1028
  unsigned short* zt = (unsigned short*)(out + ZT_OFF);
  const int mg = blockIdx.x;         // 0..15 (16-row group)
  const int b  = blockIdx.y;         // 0..31
  const int t = threadIdx.x;
  #pragma unroll
  for (int i = 0; i < 16; i++) {     // row m=i, q=t: coalesced float4 loads
    float4 v = *(const float4*)(z + (size_t)b * 262144 + (size_t)(mg * 16 + i) * 1024 + 4 * t);
    *(float4*)&tile[i][4 * t] = v;
  }
  __syncthreads();
  const int m = t & 15, w0 = (t >> 4) & 3;   // R = t&63 spans (m,w0)
  const int n = w0 * 256 + mg * 16 + m;
  #pragma unroll
  for (int i = 0; i < 8; i++) {
    int g = 4 * i + (t >> 6);        // 0..31: 8-channel group
    int c0 = 8 * g;
    unsigned short o[8];
    #pragma unroll
    for (int j = 0; j < 8; j++)
      o[j] = bf16rne(tile[m][4 * (c0 + j) + w0]);
    *(uint4*)(zt + ((size_t)(b * 1024 + n)) * 256 + c0) = *(const uint4*)o;
  }
}

// ---------------------------------------------------------------------------
// kmain: MFMA approximate distances + provably-sound exact rescreen.
// R8 change: ONE variable vs R7 — __launch_bounds__(256, 1).
// Diagnosis of R2/R6/R7's identical failures: VGPR_Count snapped to exactly
// 128 + huge scratch.  With MFMA/AGPR usage, the gfx950 backend splits the
// per-wave budget evenly arch/acc; at (256,2) budget = 512/2 = 256 total ->
// 128 ARCH cap.  R7's dbuf live set (~165 arch) spilled at that boundary.
// (256,1) -> budget 512 -> arch cap 256; actual usage ~200 still leaves
// 2 waves/SIMD (512/200 >= 2), and LDS (78KB) caps at 2 blocks/CU anyway —
// occupancy unchanged, spill gone.  Code otherwise byte-identical to R7;
// numerics proven (absmax=0 in R2-R7).
// Spill canary: VGPR_Count must NOT read 128; WRITE_SIZE must be ~128KB.
// ---------------------------------------------------------------------------
__global__ __launch_bounds__(256, 1) void kmain(const float* __restrict__ z,
                                                const float* __restrict__ E,
                                                float* __restrict__ out) {
  __shared__ __attribute__((aligned(16))) float VsT[256][65];  // exact z, [c][p]
  __shared__ __attribute__((aligned(16))) float szs[64];
  __shared__ __attribute__((aligned(16))) float dmins[64];
  __shared__ int   candK[64 * CAP];
  __shared__ float candD[64 * CAP];
  __shared__ int   cnt[64];

  const int t = threadIdx.x;
  const int ccg = blockIdx.x, b = blockIdx.y;
  const int cc0 = ccg * 16;
  const int lane = t & 63, w = t >> 6;
  const int r = t & 15, h = (t >> 4) & 3;
  const int w16r = w * 16 + r;
  const float* zb = z + (size_t)b * 262144;
  const float* se_g = out;
  const unsigned short* e1s = (const unsigned short*)(out + E1_OFF);
  const unsigned short* zt = (const unsigned short*)(out + ZT_OFF);

  if (t < 64) { cnt[t] = 0; dmins[t] = 3.4e38f; }

  // ---- stage VsT[c][p] = z[row cc0+i][4c+w0], p = 4i+w0 ----
  #pragma unroll
  for (int i = 0; i < 16; i++) {
    float4 v = *(const float4*)(zb + (cc0 + i) * 1024 + 4 * t);
    *(float4*)&VsT[t][4 * i] = v;
  }
  __syncthreads();

  // ---- sz: exact ascending-c chain; 16 px per wave (lanes 0-15) ----
  if (lane < 16) {
    const int p = w * 16 + lane;
    float a = 0.0f;
    #pragma unroll 8
    for (int c = 0; c < 256; c++)
      a = __fadd_rn(a, __fmul_rn(VsT[c][p], VsT[c][p]));
    szs[p] = a;
  }
  __syncthreads();

  // B prefetch macro: load tile (4*TIN + w) into BDST
#define BPREF(TIN, BDST)                                                      \
    {                                                                         \
      const unsigned short* bp =                                              \
          e1s + (size_t)(4 * ((TIN) & 15) + w) * 4096 + (size_t)lane * 8;     \
      _Pragma("unroll")                                                       \
      for (int s = 0; s < 8; s++) BDST[s] = *(const v8s*)(bp + 512 * s);      \
    }

  // ======== phase 1: min scan (branchless; B double-buffered) ========
  #pragma unroll 1
  for (int Tp = 0; Tp < 2; Tp++) {
    const int T0 = 2 * Tp, T1 = T0 + 1;
    v8s A0[8], A1[8];
    {
      const unsigned short* a0p =
          zt + ((size_t)(b * 1024 + T0 * 256 + cc0 + r)) * 256 + 8 * h;
      const unsigned short* a1p = a0p + 256 * 256;   // T1 = T0+1
      #pragma unroll
      for (int s = 0; s < 8; s++) {
        A0[s] = *(const v8s*)(a0p + 32 * s);
        A1[s] = *(const v8s*)(a1p + 32 * s);
      }
    }
    float sz0[4], sz1[4], b0[4], b1[4];
    #pragma unroll
    for (int reg = 0; reg < 4; reg++) {
      sz0[reg] = szs[16 * h + 4 * reg + T0];
      sz1[reg] = szs[16 * h + 4 * reg + T1];
      b0[reg] = 3.4e38f; b1[reg] = 3.4e38f;
    }

    v8s Ba[8], Bb[8];
    BPREF(0, Ba);

#define P1BODY(TI, BCUR, BNXT)                                                \
    {                                                                         \
      BPREF((TI) + 1, BNXT);                                                  \
      v4f acc0 = (v4f){0.f, 0.f, 0.f, 0.f};                                   \
      v4f acc1 = (v4f){0.f, 0.f, 0.f, 0.f};                                   \
      _Pragma("unroll")                                                       \
      for (int s = 0; s < 8; s++) {                                           \
        acc0 = __builtin_amdgcn_mfma_f32_16x16x32_bf16(A0[s], BCUR[s], acc0, 0, 0, 0); \
        acc1 = __builtin_amdgcn_mfma_f32_16x16x32_bf16(A1[s], BCUR[s], acc1, 0, 0, 0); \
      }                                                                       \
      float se_l = se_g[(TI) * 64 + w16r];                                    \
      _Pragma("unroll")                                                       \
      for (int reg = 0; reg < 4; reg++) {                                     \
        b0[reg] = fminf(b0[reg], (se_l + sz0[reg]) - 2.0f * acc0[reg]);       \
        b1[reg] = fminf(b1[reg], (se_l + sz1[reg]) - 2.0f * acc1[reg]);       \
      }                                                                       \
    }

    #pragma unroll
    for (int td = 0; td < 8; td++) {
      P1BODY(2 * td, Ba, Bb);
      P1BODY(2 * td + 1, Bb, Ba);
    }
#undef P1BODY

    #pragma unroll
    for (int reg = 0; reg < 4; reg++) {
      atomicMin((int*)&dmins[16 * h + 4 * reg + T0], __float_as_int(b0[reg]));
      atomicMin((int*)&dmins[16 * h + 4 * reg + T1], __float_as_int(b1[reg]));
    }
  }
  __syncthreads();   // dmins exact-final

  // ======== phase 2: recompute dd, append dd <= dmin + W ========
  #pragma unroll 1
  for (int Tp = 0; Tp < 2; Tp++) {
    const int T0 = 2 * Tp, T1 = T0 + 1;
    v8s A0[8], A1[8];
    {
      const unsigned short* a0p =
          zt + ((size_t)(b * 1024 + T0 * 256 + cc0 + r)) * 256 + 8 * h;
      const unsigned short* a1p = a0p + 256 * 256;
      #pragma unroll
      for (int s = 0; s < 8; s++) {
        A0[s] = *(const v8s*)(a0p + 32 * s);
        A1[s] = *(const v8s*)(a1p + 32 * s);
      }
    }
    float sz0[4], sz1[4], th0[4], th1[4];
    #pragma unroll
    for (int reg = 0; reg < 4; reg++) {
      sz0[reg] = szs[16 * h + 4 * reg + T0];
      sz1[reg] = szs[16 * h + 4 * reg + T1];
      th0[reg] = dmins[16 * h + 4 * reg + T0] + WWIN;
      th1[reg] = dmins[16 * h + 4 * reg + T1] + WWIN;
    }

    v8s Ba[8], Bb[8];
    BPREF(0, Ba);

#define P2BODY(TI, BCUR, BNXT)                                                \
    {                                                                         \
      BPREF((TI) + 1, BNXT);                                                  \
      v4f acc0 = (v4f){0.f, 0.f, 0.f, 0.f};                                   \
      v4f acc1 = (v4f){0.f, 0.f, 0.f, 0.f};                                   \
      _Pragma("unroll")                                                       \
      for (int s = 0; s < 8; s++) {                                           \
        acc0 = __builtin_amdgcn_mfma_f32_16x16x32_bf16(A0[s], BCUR[s], acc0, 0, 0, 0); \
        acc1 = __builtin_amdgcn_mfma_f32_16x16x32_bf16(A1[s], BCUR[s], acc1, 0, 0, 0); \
      }                                                                       \
      float se_l = se_g[(TI) * 64 + w16r];                                    \
      const int kl = (TI) * 64 + w16r;                                        \
      _Pragma("unroll")                                                       \
      for (int reg = 0; reg < 4; reg++) {                                     \
        float dd0 = (se_l + sz0[reg]) - 2.0f * acc0[reg];                     \
        if (dd0 <= th0[reg]) {                                                \
          int p = 16 * h + 4 * reg + T0;                                      \
          int o = atomicAdd(&cnt[p], 1);                                      \
          if (o < CAP) { candK[p*CAP+o] = kl; candD[p*CAP+o] = dd0; }         \
        }                                                                     \
        float dd1 = (se_l + sz1[reg]) - 2.0f * acc1[reg];                     \
        if (dd1 <= th1[reg]) {                                                \
          int p = 16 * h + 4 * reg + T1;                                      \
          int o = atomicAdd(&cnt[p], 1);                                      \
          if (o < CAP) { candK[p*CAP+o] = kl; candD[p*CAP+o] = dd1; }         \
        }                                                                     \
      }                                                                       \
    }

    #pragma unroll
    for (int td = 0; td < 8; td++) {
      P2BODY(2 * td, Ba, Bb);
      P2BODY(2 * td + 1, Bb, Ba);
    }
#undef P2BODY
  }
#undef BPREF
  __syncthreads();   // all appends visible

  // ---- exact rescreen: bit-identical fp32 chain for surviving candidates ----
  for (int i = t; i < 64 * CAP; i += 256) {
    int p = i / CAP, slot = i - p * CAP;
    int cn = cnt[p];
    if (cn > CAP || slot >= cn) continue;     // overflow px -> fallback
    int k = candK[i];
    const float* er = E + (size_t)k * 256;
    float dot = 0.0f;
    #pragma unroll 8
    for (int c = 0; c < 256; c++)
      dot = __fmaf_rn(VsT[c][p], er[c], dot);
    candD[i] = __fsub_rn(__fadd_rn(se_g[k], szs[p]), __fmul_rn(2.0f, dot));
  }
  __syncthreads();

  // ---- winners: lexicographic (d,k) min == first-index argmin ----
  if (t < 64) {
    int p = t, cn = cnt[p];
    if (cn <= CAP) {
      float bd = 3.4e38f; int bi = 0x7FFFFFFF;
      for (int s2 = 0; s2 < cn; s2++) {
        float d2 = candD[p * CAP + s2]; int k2 = candK[p * CAP + s2];
        if (d2 < bd || (d2 == bd && k2 < bi)) { bd = d2; bi = k2; }
      }
      int rr = p >> 2, w0 = p & 3;
      out[IDX_OFF + b * 1024 + (w0 * 256 + cc0 + rr)] = (float)bi;
    }
  }

  // ---- fallback: overflowed px -> exact full scan by one wave (dead code
  // in practice: exact-final threshold, lambda ~ 3/px, P(>24) ~ 1e-12) ----
  for (int p = 0; p < 64; p++) {
    if (cnt[p] > CAP && (p & 3) == w) {
      float bd = 3.4e38f; int bi = 0x7FFFFFFF;
      for (int k = lane; k < 1024; k += 64) {
        const float* er = E + (size_t)k * 256;
        float dot = 0.0f;
        #pragma unroll 8
        for (int c = 0; c < 256; c++)
          dot = __fmaf_rn(VsT[c][p], er[c], dot);
        float d2 = __fsub_rn(__fadd_rn(se_g[k], szs[p]), __fmul_rn(2.0f, dot));
        if (d2 < bd || (d2 == bd && k < bi)) { bd = d2; bi = k; }
      }
      #pragma unroll
      for (int mm = 32; mm >= 1; mm >>= 1) {
        float d2 = __shfl_xor(bd, mm, 64);
        int i2 = __shfl_xor(bi, mm, 64);
        if (d2 < bd || (d2 == bd && i2 < bi)) { bd = d2; bi = i2; }
      }
      if (lane == 0) {
        int rr = p >> 2, w0 = p & 3;
        out[IDX_OFF + b * 1024 + (w0 * 256 + cc0 + rr)] = (float)bi;
      }
    }
  }
}

// ---------------------------------------------------------------------------
// kout: z_q_st = fl(zp + fl(zq - zp)); per-block loss partial -> d_ws
// ---------------------------------------------------------------------------
__global__ __launch_bounds__(256) void kout(const float* __restrict__ z,
                                            const float* __restrict__ E,
                                            float* __restrict__ out,
                                            float* __restrict__ ws) {
  __shared__ float red[4];
  const int t = threadIdx.x;
  const size_t g4 = (size_t)blockIdx.x * 256 + t;
  const size_t g = g4 * 4;
  const int b = (int)(g >> 18);
  const int c = (int)((g >> 10) & 255);
  const int n = (int)(g & 1023);

  float4 zp = *(const float4*)(z + g);
  float4 idxf = *(const float4*)(out + IDX_OFF + b * 1024 + n);
  int i0 = (int)idxf.x, i1 = (int)idxf.y, i2 = (int)idxf.z, i3 = (int)idxf.w;
  float q0 = E[i0 * 256 + c];
  float q1 = E[i1 * 256 + c];
  float q2 = E[i2 * 256 + c];
  float q3 = E[i3 * 256 + c];
  float d0 = __fsub_rn(q0, zp.x);
  float d1 = __fsub_rn(q1, zp.y);
  float d2 = __fsub_rn(q2, zp.z);
  float d3 = __fsub_rn(q3, zp.w);
  float4 o;
  o.x = __fadd_rn(zp.x, d0);
  o.y = __fadd_rn(zp.y, d1);
  o.z = __fadd_rn(zp.z, d2);
  o.w = __fadd_rn(zp.w, d3);
  *(float4*)(out + g) = o;

  float s = d0 * d0 + d1 * d1 + d2 * d2 + d3 * d3;
  #pragma unroll
  for (int off = 32; off > 0; off >>= 1) s += __shfl_down(s, off);
  if ((t & 63) == 0) red[t >> 6] = s;
  __syncthreads();
  if (t == 0) ws[blockIdx.x] = red[0] + red[1] + red[2] + red[3];
}

// ---------------------------------------------------------------------------
// kfin: loss = 1.25 * (sum(ws)/N)
// ---------------------------------------------------------------------------
__global__ __launch_bounds__(256) void kfin(const float* __restrict__ ws,
                                            float* __restrict__ out) {
  __shared__ float red[4];
  const int t = threadIdx.x;
  float s = 0.0f;
  #pragma unroll
  for (int i = 0; i < 32; i++) s += ws[t + 256 * i];
  #pragma unroll
  for (int off = 32; off > 0; off >>= 1) s += __shfl_down(s, off);
  if ((t & 63) == 0) red[t >> 6] = s;
  __syncthreads();
  if (t == 0) {
    float S = red[0] + red[1] + red[2] + red[3];
    float m = S / 8388608.0f;
    out[LOSS_OFF] = __fadd_rn(m, __fmul_rn(0.25f, m));
  }
}

extern "C" void kernel_launch(void* const* d_in, const int* in_sizes, int n_in,
                              void* d_out, int out_size, void* d_ws, size_t ws_size,
                              hipStream_t stream) {
  const float* z = (const float*)d_in[0];    // [32,256,32,32]
  const float* E = (const float*)d_in[1];    // [1024,256]
  float* out = (float*)d_out;
  float* ws = (float*)d_ws;

  ktr<<<dim3(16, 4), 256, 0, stream>>>(E, out);
  kse<<<dim3(4), 256, 0, stream>>>(out);
  kes<<<dim3(64), 256, 0, stream>>>(E, out);
  kzt<<<dim3(16, 32), 256, 0, stream>>>(z, out);
  kmain<<<dim3(16, 32), 256, 0, stream>>>(z, E, out);
  kout<<<dim3(8192), 256, 0, stream>>>(z, E, out, ws);
  kfin<<<dim3(1), 256, 0, stream>>>(ws, out);
}

// Round 9
// 304.418 us; speedup vs baseline: 12.4328x; 1.3996x over previous
//
#include <hip/hip_runtime.h>
#include <stdint.h>

// Problem constants
#define ZSIZE   8388608      // 32*256*32*32
#define NPIX    32768        // 32*32*32
#define IDX_OFF ZSIZE        // idx output offset (floats) in d_out
#define LOSS_OFF (ZSIZE + NPIX)
#define ET_OFF  1024         // Et fp32 [256][1024] scratch (for kse)
#define E1_OFF  263168       // e1s swizzled bf16 (131072 floats = 512 KB)
#define ZT_OFF  394240       // zt bf16 [32][1024][256] (4194304 floats)
#define CAP     24           // candidate slots per pixel
#define WWIN    6.0e-3f      // window >= 2*eps_bound (eps<=2.4e-3 rigorous)

using v8s = __attribute__((ext_vector_type(8))) short;   // 8 bf16 (4 VGPR)
using v4f = __attribute__((ext_vector_type(4))) float;   // MFMA acc

__device__ __forceinline__ unsigned short bf16rne(float f) {
  unsigned u = __float_as_uint(f);
  return (unsigned short)((u + 0x7FFFu + ((u >> 16) & 1u)) >> 16);
}

// ---------------------------------------------------------------------------
// ktr: transpose embedding E[1024][256] -> Et[256][1024] (feeds kse only)
// ---------------------------------------------------------------------------
__global__ __launch_bounds__(256) void ktr(const float* __restrict__ E,
                                           float* __restrict__ out) {
  __shared__ float tile[64][65];
  const int k0 = blockIdx.x * 64;
  const int c0 = blockIdx.y * 64;
  const int t = threadIdx.x;
  #pragma unroll
  for (int i = 0; i < 4; i++) {
    int f = t + 256 * i;
    int r = f >> 4, q = f & 15;
    float4 e = *(const float4*)(E + (k0 + r) * 256 + c0 + 4 * q);
    tile[r][4 * q + 0] = e.x; tile[r][4 * q + 1] = e.y;
    tile[r][4 * q + 2] = e.z; tile[r][4 * q + 3] = e.w;
  }
  __syncthreads();
  #pragma unroll
  for (int i = 0; i < 4; i++) {
    int f = t + 256 * i;
    int cr = f >> 4, kq = f & 15;
    float4 o;
    o.x = tile[4 * kq + 0][cr];
    o.y = tile[4 * kq + 1][cr];
    o.z = tile[4 * kq + 2][cr];
    o.w = tile[4 * kq + 3][cr];
    *(float4*)(out + ET_OFF + (c0 + cr) * 1024 + k0 + 4 * kq) = o;
  }
}

// ---------------------------------------------------------------------------
// kse: se[k] = ascending-c sequential fp32 chain of E[k][c]^2 (bit-faithful)
// ---------------------------------------------------------------------------
__global__ __launch_bounds__(256) void kse(float* __restrict__ out) {
  const int k = blockIdx.x * 256 + threadIdx.x;
  const float* Et = out + ET_OFF;
  float acc = 0.0f;
  #pragma unroll 8
  for (int c = 0; c < 256; c++) {
    float v = Et[c * 1024 + k];
    acc = __fadd_rn(acc, __fmul_rn(v, v));
  }
  out[k] = acc;
}

// ---------------------------------------------------------------------------
// kes: swizzled bf16 embedding in MFMA B-fragment order.
// e1s[tile][s][lane] (16B chunks): tile = code0/16 (0..63), s = 0..7,
// lane = 0..63 (r=lane&15, h=(lane>>4)&3).
// chunk = bf16(E[16*tile + r][8*h + 32*s + 0..7]).
// A wave's B-load for (tile,s) is 64 lanes x 16B = 1KB contiguous.
// ---------------------------------------------------------------------------
__global__ __launch_bounds__(256) void kes(const float* __restrict__ E,
                                           float* __restrict__ out) {
  unsigned short* e1s = (unsigned short*)(out + E1_OFF);
  const int tile = blockIdx.x;       // 0..63
  const int t = threadIdx.x;
  #pragma unroll
  for (int i = 0; i < 2; i++) {
    int chunk = t + 256 * i;         // 0..511
    int s = chunk >> 6, lane = chunk & 63;
    int r = lane & 15, h = (lane >> 4) & 3;
    const float* src = E + (16 * tile + r) * 256 + 8 * h + 32 * s;
    unsigned short o[8];
    #pragma unroll
    for (int j = 0; j < 8; j++) o[j] = bf16rne(src[j]);
    *(uint4*)(e1s + (size_t)tile * 4096 + (size_t)chunk * 8) = *(const uint4*)o;
  }
}

// ---------------------------------------------------------------------------
// kzt: zt[b][n][c] = bf16_rne(zz[c][n]).  n = w0*256 + m.  Row n holds 256
// contiguous bf16 channels -> A-frag loads are per-lane 16B contiguous.
// ---------------------------------------------------------------------------
__global__ __launch_bounds__(256) void kzt(const float* __restrict__ z,
                                           float* __restrict__ out) {
  __shared__ float tile[16][1028];   // 16 z-rows x 1024, pad 1028
  unsigned short* zt = (unsigned short*)(out + ZT_OFF);
  const int mg = blockIdx.x;         // 0..15 (16-row group)
  const int b  = blockIdx.y;         // 0..31
  const int t = threadIdx.x;
  #pragma unroll
  for (int i = 0; i < 16; i++) {     // row m=i, q=t: coalesced float4 loads
    float4 v = *(const float4*)(z + (size_t)b * 262144 + (size_t)(mg * 16 + i) * 1024 + 4 * t);
    *(float4*)&tile[i][4 * t] = v;
  }
  __syncthreads();
  const int m = t & 15, w0 = (t >> 4) & 3;   // R = t&63 spans (m,w0)
  const int n = w0 * 256 + mg * 16 + m;
  #pragma unroll
  for (int i = 0; i < 8; i++) {
    int g = 4 * i + (t >> 6);        // 0..31: 8-channel group
    int c0 = 8 * g;
    unsigned short o[8];
    #pragma unroll
    for (int j = 0; j < 8; j++)
      o[j] = bf16rne(tile[m][4 * (c0 + j) + w0]);
    *(uint4*)(zt + ((size_t)(b * 1024 + n)) * 256 + c0) = *(const uint4*)o;
  }
}

// ---------------------------------------------------------------------------
// kmain: MFMA approximate distances + provably-sound exact rescreen.
// R9 change: R6/R7/R8 all lost to the register allocator (unrolled
// dbuf + hoisted loads -> spill at any cap).  Revert the hot loop to the
// PROVEN R5 form (VGPR 92, zero scratch) and attack the latency stall with
// TLP instead of ILP: drop VsT (66.5 KB of the 78 KB LDS) and read the
// exact z values straight from global in sz/rescreen/fallback (same fp32
// dwords, same chain order -> bit-identical; z tile = 64 KB/block,
// L1/L2-hot).  LDS 78 KB -> ~13 KB: occupancy goes LDS-capped-2-blocks/CU
// -> VGPR-bound ~4 blocks/CU = 2x latency-hiding TLP for the same K-loop.
// Canaries: VGPR ~92-110 (NOT 128/256), WRITE_SIZE ~128 KB.
// ---------------------------------------------------------------------------
__global__ __launch_bounds__(256, 2) void kmain(const float* __restrict__ z,
                                                const float* __restrict__ E,
                                                float* __restrict__ out) {
  __shared__ __attribute__((aligned(16))) float szs[64];
  __shared__ __attribute__((aligned(16))) float dmins[64];
  __shared__ int   candK[64 * CAP];
  __shared__ float candD[64 * CAP];
  __shared__ int   cnt[64];

  const int t = threadIdx.x;
  const int ccg = blockIdx.x, b = blockIdx.y;
  const int cc0 = ccg * 16;
  const int lane = t & 63, w = t >> 6;
  const int r = t & 15, h = (t >> 4) & 3;
  const int w16r = w * 16 + r;
  const float* zb = z + (size_t)b * 262144;
  const float* se_g = out;
  const unsigned short* e1s = (const unsigned short*)(out + E1_OFF);
  const unsigned short* zt = (const unsigned short*)(out + ZT_OFF);

  if (t < 64) { cnt[t] = 0; dmins[t] = 3.4e38f; }

  // ---- sz: exact ascending-c chain; 16 px per wave (lanes 0-15).
  // z column for px p: zb[(cc0 + (p>>2))*1024 + 4c + (p&3)] — same fp32
  // values VsT held, same order -> bit-identical szs. ----
  if (lane < 16) {
    const int p = w * 16 + lane;
    const float* zp = zb + (cc0 + (p >> 2)) * 1024 + (p & 3);
    float a = 0.0f;
    #pragma unroll 8
    for (int c = 0; c < 256; c++) {
      float v = zp[4 * c];
      a = __fadd_rn(a, __fmul_rn(v, v));
    }
    szs[p] = a;
  }
  __syncthreads();

  // ---- per-lane se for its 16 codes (independent of T) ----
  float se16r[16];
  #pragma unroll
  for (int ti = 0; ti < 16; ti++) se16r[ti] = se_g[ti * 64 + w16r];

  // ======== phase 1: min scan (R5 form — branchless, no dbuf) ========
  #pragma unroll 1
  for (int Tp = 0; Tp < 2; Tp++) {
    const int T0 = 2 * Tp, T1 = T0 + 1;
    v8s A0[8], A1[8];
    {
      const unsigned short* a0p =
          zt + ((size_t)(b * 1024 + T0 * 256 + cc0 + r)) * 256 + 8 * h;
      const unsigned short* a1p = a0p + 256 * 256;   // T1 = T0+1
      #pragma unroll
      for (int s = 0; s < 8; s++) {
        A0[s] = *(const v8s*)(a0p + 32 * s);
        A1[s] = *(const v8s*)(a1p + 32 * s);
      }
    }
    float sz0[4], sz1[4], b0[4], b1[4];
    #pragma unroll
    for (int reg = 0; reg < 4; reg++) {
      sz0[reg] = szs[16 * h + 4 * reg + T0];
      sz1[reg] = szs[16 * h + 4 * reg + T1];
      b0[reg] = 3.4e38f; b1[reg] = 3.4e38f;
    }

    #pragma unroll 4
    for (int ti = 0; ti < 16; ti++) {
      const unsigned short* bb = e1s + (size_t)(4 * ti + w) * 4096 + (size_t)lane * 8;
      v4f acc0 = (v4f){0.f, 0.f, 0.f, 0.f};
      v4f acc1 = (v4f){0.f, 0.f, 0.f, 0.f};
      #pragma unroll
      for (int s = 0; s < 8; s++) {
        v8s B_ = *(const v8s*)(bb + 512 * s);
        acc0 = __builtin_amdgcn_mfma_f32_16x16x32_bf16(A0[s], B_, acc0, 0, 0, 0);
        acc1 = __builtin_amdgcn_mfma_f32_16x16x32_bf16(A1[s], B_, acc1, 0, 0, 0);
      }
      float se_l = se16r[ti];
      #pragma unroll
      for (int reg = 0; reg < 4; reg++) {
        b0[reg] = fminf(b0[reg], (se_l + sz0[reg]) - 2.0f * acc0[reg]);
        b1[reg] = fminf(b1[reg], (se_l + sz1[reg]) - 2.0f * acc1[reg]);
      }
    }
    #pragma unroll
    for (int reg = 0; reg < 4; reg++) {
      atomicMin((int*)&dmins[16 * h + 4 * reg + T0], __float_as_int(b0[reg]));
      atomicMin((int*)&dmins[16 * h + 4 * reg + T1], __float_as_int(b1[reg]));
    }
  }
  __syncthreads();   // dmins exact-final

  // ======== phase 2: recompute dd, append dd <= dmin + W (R5 form) ========
  #pragma unroll 1
  for (int Tp = 0; Tp < 2; Tp++) {
    const int T0 = 2 * Tp, T1 = T0 + 1;
    v8s A0[8], A1[8];
    {
      const unsigned short* a0p =
          zt + ((size_t)(b * 1024 + T0 * 256 + cc0 + r)) * 256 + 8 * h;
      const unsigned short* a1p = a0p + 256 * 256;
      #pragma unroll
      for (int s = 0; s < 8; s++) {
        A0[s] = *(const v8s*)(a0p + 32 * s);
        A1[s] = *(const v8s*)(a1p + 32 * s);
      }
    }
    float sz0[4], sz1[4], th0[4], th1[4];
    #pragma unroll
    for (int reg = 0; reg < 4; reg++) {
      sz0[reg] = szs[16 * h + 4 * reg + T0];
      sz1[reg] = szs[16 * h + 4 * reg + T1];
      th0[reg] = dmins[16 * h + 4 * reg + T0] + WWIN;
      th1[reg] = dmins[16 * h + 4 * reg + T1] + WWIN;
    }

    #pragma unroll 4
    for (int ti = 0; ti < 16; ti++) {
      const unsigned short* bb = e1s + (size_t)(4 * ti + w) * 4096 + (size_t)lane * 8;
      v4f acc0 = (v4f){0.f, 0.f, 0.f, 0.f};
      v4f acc1 = (v4f){0.f, 0.f, 0.f, 0.f};
      #pragma unroll
      for (int s = 0; s < 8; s++) {
        v8s B_ = *(const v8s*)(bb + 512 * s);
        acc0 = __builtin_amdgcn_mfma_f32_16x16x32_bf16(A0[s], B_, acc0, 0, 0, 0);
        acc1 = __builtin_amdgcn_mfma_f32_16x16x32_bf16(A1[s], B_, acc1, 0, 0, 0);
      }
      float se_l = se16r[ti];
      const int kl = ti * 64 + w16r;
      #pragma unroll
      for (int reg = 0; reg < 4; reg++) {
        float dd0 = (se_l + sz0[reg]) - 2.0f * acc0[reg];
        if (dd0 <= th0[reg]) {
          int p = 16 * h + 4 * reg + T0;
          int o = atomicAdd(&cnt[p], 1);
          if (o < CAP) { candK[p * CAP + o] = kl; candD[p * CAP + o] = dd0; }
        }
        float dd1 = (se_l + sz1[reg]) - 2.0f * acc1[reg];
        if (dd1 <= th1[reg]) {
          int p = 16 * h + 4 * reg + T1;
          int o = atomicAdd(&cnt[p], 1);
          if (o < CAP) { candK[p * CAP + o] = kl; candD[p * CAP + o] = dd1; }
        }
      }
    }
  }
  __syncthreads();   // all appends visible

  // ---- exact rescreen: bit-identical fp32 chain; z read from global ----
  for (int i = t; i < 64 * CAP; i += 256) {
    int p = i / CAP, slot = i - p * CAP;
    int cn = cnt[p];
    if (cn > CAP || slot >= cn) continue;     // overflow px -> fallback
    int k = candK[i];
    const float* er = E + (size_t)k * 256;
    const float* zp = zb + (cc0 + (p >> 2)) * 1024 + (p & 3);
    float dot = 0.0f;
    #pragma unroll 8
    for (int c = 0; c < 256; c++)
      dot = __fmaf_rn(zp[4 * c], er[c], dot);
    candD[i] = __fsub_rn(__fadd_rn(se_g[k], szs[p]), __fmul_rn(2.0f, dot));
  }
  __syncthreads();

  // ---- winners: lexicographic (d,k) min == first-index argmin ----
  if (t < 64) {
    int p = t, cn = cnt[p];
    if (cn <= CAP) {
      float bd = 3.4e38f; int bi = 0x7FFFFFFF;
      for (int s2 = 0; s2 < cn; s2++) {
        float d2 = candD[p * CAP + s2]; int k2 = candK[p * CAP + s2];
        if (d2 < bd || (d2 == bd && k2 < bi)) { bd = d2; bi = k2; }
      }
      int rr = p >> 2, w0 = p & 3;
      out[IDX_OFF + b * 1024 + (w0 * 256 + cc0 + rr)] = (float)bi;
    }
  }

  // ---- fallback: overflowed px -> exact full scan by one wave (dead code
  // in practice: exact-final threshold, lambda ~ 3/px, P(>24) ~ 1e-12) ----
  for (int p = 0; p < 64; p++) {
    if (cnt[p] > CAP && (p & 3) == w) {
      const float* zp = zb + (cc0 + (p >> 2)) * 1024 + (p & 3);
      float bd = 3.4e38f; int bi = 0x7FFFFFFF;
      for (int k = lane; k < 1024; k += 64) {
        const float* er = E + (size_t)k * 256;
        float dot = 0.0f;
        #pragma unroll 8
        for (int c = 0; c < 256; c++)
          dot = __fmaf_rn(zp[4 * c], er[c], dot);
        float d2 = __fsub_rn(__fadd_rn(se_g[k], szs[p]), __fmul_rn(2.0f, dot));
        if (d2 < bd || (d2 == bd && k < bi)) { bd = d2; bi = k; }
      }
      #pragma unroll
      for (int mm = 32; mm >= 1; mm >>= 1) {
        float d2 = __shfl_xor(bd, mm, 64);
        int i2 = __shfl_xor(bi, mm, 64);
        if (d2 < bd || (d2 == bd && i2 < bi)) { bd = d2; bi = i2; }
      }
      if (lane == 0) {
        int rr = p >> 2, w0 = p & 3;
        out[IDX_OFF + b * 1024 + (w0 * 256 + cc0 + rr)] = (float)bi;
      }
    }
  }
}

// ---------------------------------------------------------------------------
// kout: z_q_st = fl(zp + fl(zq - zp)); per-block loss partial -> d_ws
// ---------------------------------------------------------------------------
__global__ __launch_bounds__(256) void kout(const float* __restrict__ z,
                                            const float* __restrict__ E,
                                            float* __restrict__ out,
                                            float* __restrict__ ws) {
  __shared__ float red[4];
  const int t = threadIdx.x;
  const size_t g4 = (size_t)blockIdx.x * 256 + t;
  const size_t g = g4 * 4;
  const int b = (int)(g >> 18);
  const int c = (int)((g >> 10) & 255);
  const int n = (int)(g & 1023);

  float4 zp = *(const float4*)(z + g);
  float4 idxf = *(const float4*)(out + IDX_OFF + b * 1024 + n);
  int i0 = (int)idxf.x, i1 = (int)idxf.y, i2 = (int)idxf.z, i3 = (int)idxf.w;
  float q0 = E[i0 * 256 + c];
  float q1 = E[i1 * 256 + c];
  float q2 = E[i2 * 256 + c];
  float q3 = E[i3 * 256 + c];
  float d0 = __fsub_rn(q0, zp.x);
  float d1 = __fsub_rn(q1, zp.y);
  float d2 = __fsub_rn(q2, zp.z);
  float d3 = __fsub_rn(q3, zp.w);
  float4 o;
  o.x = __fadd_rn(zp.x, d0);
  o.y = __fadd_rn(zp.y, d1);
  o.z = __fadd_rn(zp.z, d2);
  o.w = __fadd_rn(zp.w, d3);
  *(float4*)(out + g) = o;

  float s = d0 * d0 + d1 * d1 + d2 * d2 + d3 * d3;
  #pragma unroll
  for (int off = 32; off > 0; off >>= 1) s += __shfl_down(s, off);
  if ((t & 63) == 0) red[t >> 6] = s;
  __syncthreads();
  if (t == 0) ws[blockIdx.x] = red[0] + red[1] + red[2] + red[3];
}

// ---------------------------------------------------------------------------
// kfin: loss = 1.25 * (sum(ws)/N)
// ---------------------------------------------------------------------------
__global__ __launch_bounds__(256) void kfin(const float* __restrict__ ws,
                                            float* __restrict__ out) {
  __shared__ float red[4];
  const int t = threadIdx.x;
  float s = 0.0f;
  #pragma unroll
  for (int i = 0; i < 32; i++) s += ws[t + 256 * i];
  #pragma unroll
  for (int off = 32; off > 0; off >>= 1) s += __shfl_down(s, off);
  if ((t & 63) == 0) red[t >> 6] = s;
  __syncthreads();
  if (t == 0) {
    float S = red[0] + red[1] + red[2] + red[3];
    float m = S / 8388608.0f;
    out[LOSS_OFF] = __fadd_rn(m, __fmul_rn(0.25f, m));
  }
}

extern "C" void kernel_launch(void* const* d_in, const int* in_sizes, int n_in,
                              void* d_out, int out_size, void* d_ws, size_t ws_size,
                              hipStream_t stream) {
  const float* z = (const float*)d_in[0];    // [32,256,32,32]
  const float* E = (const float*)d_in[1];    // [1024,256]
  float* out = (float*)d_out;
  float* ws = (float*)d_ws;

  ktr<<<dim3(16, 4), 256, 0, stream>>>(E, out);
  kse<<<dim3(4), 256, 0, stream>>>(out);
  kes<<<dim3(64), 256, 0, stream>>>(E, out);
  kzt<<<dim3(16, 32), 256, 0, stream>>>(z, out);
  kmain<<<dim3(16, 32), 256, 0, stream>>>(z, E, out);
  kout<<<dim3(8192), 256, 0, stream>>>(z, E, out, ws);
  kfin<<<dim3(1), 256, 0, stream>>>(ws, out);
}